// Round 7
// baseline (302.468 us; speedup 1.0000x reference)
//
#include <hip/hip_runtime.h>
#include <hip/hip_bf16.h>
#include <stdint.h>

#define N_NODES 8192
#define IN_F    256
#define HD      64
#define NH      2
#define MS      8                        // column splits
#define SLICE   1024                     // cols per block
#define NT      16                       // 64-col tiles per block
#define ALPHA   0.2f

typedef __attribute__((ext_vector_type(8))) short bf16x8s;
typedef __attribute__((ext_vector_type(4))) float f32x4;

// ws layout (bytes)
#define OFF_U      0          // u[h][v][256] f32                   : 4 KB
#define OFF_WFRAG  4096       // W frag-order [8][8][64][8] bf16    : 64 KB
#define OFF_F1     69632      // f1[2][8192] f32                    : 64 KB
#define OFF_F2     135168     // f2[2][8192] f32                    : 64 KB
#define OFF_F2MAX  200704     // f2max[2] f32 (+pad)
#define OFF_G2     200960     // g2[2][8192] float2                 : 128 KB
#define OFF_WHB    332032     // Wh frag-order [2][128][2][4][64][8] bf16 : 2 MB
#define OFF_OP     2429184    // O partials [MS][2][8192][64] f32   : 32 MB
#define OFF_LP     35983616   // L partials [MS][2][8192] f32       : 512 KB

__device__ __forceinline__ unsigned short f2bf(float x) {
  union { float f; uint32_t u; } c; c.f = x;
  uint32_t r = c.u + 0x7FFFu + ((c.u >> 16) & 1u);   // RNE
  return (unsigned short)(r >> 16);
}
__device__ __forceinline__ short f2bfs(float x) {
  __hip_bfloat16 b = __float2bfloat16(x);
  return __builtin_bit_cast(short, b);
}

// ---------------- kernel 1: u = W·a (f32) + W repacked to B-fragment order (bf16)
__global__ void gat_prep_kernel(const float* __restrict__ W, const float* __restrict__ a,
                                float* __restrict__ u, unsigned short* __restrict__ wfrag)
{
  int idx = blockIdx.x * 256 + threadIdx.x;
  if (idx < 32768) {
    int j = idx & 7, lane = (idx >> 3) & 63, ks = (idx >> 9) & 7, Dt = idx >> 12;
    int k  = ks * 32 + ((lane >> 4) << 3) + j;
    int dp = Dt * 16 + (lane & 15);
    int hh = dp >> 6, d = dp & 63;
    wfrag[idx] = f2bf(W[(size_t)(hh * IN_F + k) * HD + d]);
  } else if (idx < 32768 + NH * 2 * IN_F) {
    int i2 = idx - 32768;
    int i = i2 & 255, v = (i2 >> 8) & 1, h = i2 >> 9;
    const float* Wp = W + (size_t)(h * IN_F + i) * HD;
    const float* ap = a + h * 2 * HD + v * HD;
    float s = 0.f;
    for (int d = 0; d < HD; ++d) s += Wp[d] * ap[d];
    u[(h * 2 + v) * IN_F + i] = s;
  }
}

// ---------------- kernel 2: f1/f2 = h·u, plus per-column exp pairs G1=exp(f2),Ga=exp(a*f2)
__global__ __launch_bounds__(256) void gat_f12_kernel(const float* __restrict__ hmat,
    const float* __restrict__ u, float* __restrict__ f1, float* __restrict__ f2,
    float2* __restrict__ g2)
{
  int n = blockIdx.x * 4 + (threadIdx.x >> 6);
  int l = threadIdx.x & 63;
  float4 hv = *(const float4*)(hmat + (size_t)n * IN_F + l * 4);
  float s[4];
#pragma unroll
  for (int q = 0; q < 4; ++q) {
    float4 uv = *(const float4*)(u + q * IN_F + l * 4);
    s[q] = hv.x * uv.x + hv.y * uv.y + hv.z * uv.z + hv.w * uv.w;
  }
#pragma unroll
  for (int off = 1; off < 64; off <<= 1) {
#pragma unroll
    for (int q = 0; q < 4; ++q) s[q] += __shfl_xor(s[q], off);
  }
  if (l == 0) {
    f1[n] = s[0];           f2[n] = s[1];
    f1[N_NODES + n] = s[2]; f2[N_NODES + n] = s[3];
    g2[n]           = make_float2(__expf(s[1]), __expf(ALPHA * s[1]));
    g2[N_NODES + n] = make_float2(__expf(s[3]), __expf(ALPHA * s[3]));
  }
}

// ---------------- kernel 3: per-head max of f2 (softmax stability bound)
__global__ void gat_f2max_kernel(const float* __restrict__ f2, float* __restrict__ f2m)
{
  int h = blockIdx.x;
  float m = -1e30f;
  for (int i = threadIdx.x; i < N_NODES; i += 256) m = fmaxf(m, f2[h * N_NODES + i]);
#pragma unroll
  for (int off = 1; off < 64; off <<= 1) m = fmaxf(m, __shfl_xor(m, off));
  __shared__ float red[4];
  if ((threadIdx.x & 63) == 0) red[threadIdx.x >> 6] = m;
  __syncthreads();
  if (threadIdx.x == 0) f2m[h] = fmaxf(fmaxf(red[0], red[1]), fmaxf(red[2], red[3]));
}

// ---------------- kernel 4: Wh = h @ W' (bf16 MFMA), epilogue in B-frag order
__global__ __launch_bounds__(256) void gat_wh_kernel(const float* __restrict__ hmat,
    const unsigned short* __restrict__ wfrag, unsigned short* __restrict__ whb)
{
  int tid = threadIdx.x;
  int w = tid >> 6, l = tid & 63;
  int n0 = blockIdx.x * 64;
  int row = n0 + w * 16 + (l & 15);
  f32x4 acc[8] = {};
#pragma unroll
  for (int ks = 0; ks < 8; ++ks) {
    const float* ap = hmat + (size_t)row * IN_F + ks * 32 + ((l >> 4) << 3);
    float av[8];
    *(float4*)&av[0] = *(const float4*)ap;
    *(float4*)&av[4] = *(const float4*)(ap + 4);
    bf16x8s af;
#pragma unroll
    for (int j = 0; j < 8; ++j) af[j] = f2bfs(av[j]);
#pragma unroll
    for (int Dt = 0; Dt < 8; ++Dt) {
      bf16x8s bfv = *(const bf16x8s*)(wfrag + ((size_t)(Dt * 8 + ks) * 64 + l) * 8);
      acc[Dt] = __builtin_amdgcn_mfma_f32_16x16x32_bf16(af, bfv, acc[Dt], 0, 0, 0);
    }
  }
  int Tm = blockIdx.x;
  int s  = w >> 1;
  int lb = ((w & 1) * 2 + ((l >> 4) >> 1)) * 16 + (l & 15);
  int jh = (l >> 4) & 1;
#pragma unroll
  for (int Dt = 0; Dt < 8; ++Dt) {
    int hh = Dt >> 2, D = Dt & 3;
    ushort4 pk;
    pk.x = f2bf(acc[Dt][0]); pk.y = f2bf(acc[Dt][1]);
    pk.z = f2bf(acc[Dt][2]); pk.w = f2bf(acc[Dt][3]);
    size_t off = ((((size_t)(hh * 128 + Tm) * 2 + s) * 4 + D) * 64 + lb) * 8 + jh * 4;
    *(ushort4*)(whb + off) = pk;
  }
}

// ---------------- kernel 5: BARRIER-FREE masked-softmax + PV.
// 16 rows per wave, waves fully independent. whb B-frags loaded directly from
// global (lane-contiguous, L2-hot) issued at iter top, consumed by MFMA at
// bottom. adj as exact per-fragment int4 reads, 2-deep register prefetch.
// Only one __syncthreads total (gl staging).
__global__ __launch_bounds__(256, 3) void gat_attn_kernel(
    const int* __restrict__ adj, const unsigned short* __restrict__ whb,
    const float* __restrict__ f1, const float2* __restrict__ g2,
    const float* __restrict__ f2max, float* __restrict__ Opart, float* __restrict__ Lpart)
{
  int bx = blockIdx.x;                 // grid = 128*MS
  int split = bx & (MS - 1);
  int T = bx >> 3;
  int tid = threadIdx.x;
  int w = tid >> 6, l = tid & 63;
  int n0 = T * 64;
  int row = n0 + w * 16 + (l & 15);
  int mbase = split * SLICE;
  int koff = (l >> 4) << 3;
  int cb = mbase >> 6;                 // whb column-tile base

  __shared__ float4 gl[2][512];        // 16 KB: G-pairs per head, whole slice

  {
    const float4* s0 = (const float4*)(g2 + mbase);
    const float4* s1 = (const float4*)(g2 + N_NODES + mbase);
    gl[0][tid] = s0[tid]; gl[0][tid + 256] = s0[tid + 256];
    gl[1][tid] = s1[tid]; gl[1][tid + 256] = s1[tid + 256];
  }

  float E1[NH], Ea[NH];
#pragma unroll
  for (int h = 0; h < NH; ++h) {
    float f1v = f1[h * N_NODES + row];
    float tm  = f1v + f2max[h];
    float mrow = fmaxf(tm, ALPHA * tm);   // lrelu(f1+f2max) >= all e in this row
    E1[h] = __expf(f1v - mrow);
    Ea[h] = __expf(ALPHA * f1v - mrow);
  }

  __syncthreads();                     // gl visible; last barrier in the kernel

  const int* adjr = adj + (size_t)row * N_NODES + mbase + koff;
  const uint4* whb4 = (const uint4*)whb;   // frag (h,Tm,s,D): index (((h*128+Tm)*2+s)*4+D)*64 + l

  // adj 2-deep register prefetch: 4 int4 per iter (exact coverage, no dup)
  int4 c0 = *(const int4*)(adjr);      int4 c1 = *(const int4*)(adjr + 4);
  int4 c2 = *(const int4*)(adjr + 32); int4 c3 = *(const int4*)(adjr + 36);
  int4 x0 = *(const int4*)(adjr + 64); int4 x1 = *(const int4*)(adjr + 68);
  int4 x2 = *(const int4*)(adjr + 96); int4 x3 = *(const int4*)(adjr + 100);

  f32x4 acc[NH][4] = {};
  float lsum[NH] = {0.f, 0.f};

#pragma unroll 2
  for (int mt = 0; mt < NT; ++mt) {
    // issue ALL whb fragment loads for this iter (consumed by MFMA below)
    uint4 wfr[NH][2][4];
#pragma unroll
    for (int h = 0; h < NH; ++h)
#pragma unroll
      for (int s = 0; s < 2; ++s)
#pragma unroll
        for (int D = 0; D < 4; ++D)
          wfr[h][s][D] = whb4[(size_t)((((h * 128 + cb + mt) * 2 + s) * 4 + D) * 64 + l)];

    int aj[16];
    *(int4*)&aj[0]  = c0; *(int4*)&aj[4]  = c1;
    *(int4*)&aj[8]  = c2; *(int4*)&aj[12] = c3;
    c0 = x0; c1 = x1; c2 = x2; c3 = x3;
    if (mt + 2 < NT) {
      const int* ap = adjr + (mt + 2) * 64;
      x0 = *(const int4*)ap;        x1 = *(const int4*)(ap + 4);
      x2 = *(const int4*)(ap + 32); x3 = *(const int4*)(ap + 36);
    }

#pragma unroll
    for (int h = 0; h < NH; ++h) {
      bf16x8s af[2];
#pragma unroll
      for (int s = 0; s < 2; ++s) {
        const float4* gp = &gl[h][(mt * 64 + s * 32 + koff) >> 1];
        float ps = 0.f;
#pragma unroll
        for (int k = 0; k < 4; ++k) {
          float4 gv = gp[k];
          float v0 = fmaxf(E1[h] * gv.x, Ea[h] * gv.y);
          float v1 = fmaxf(E1[h] * gv.z, Ea[h] * gv.w);
          float p0 = (aj[s * 8 + 2 * k]     > 0) ? v0 : 0.f;
          float p1 = (aj[s * 8 + 2 * k + 1] > 0) ? v1 : 0.f;
          ps += p0 + p1;
          af[s][2 * k] = f2bfs(p0); af[s][2 * k + 1] = f2bfs(p1);
        }
        lsum[h] += ps;
      }
#pragma unroll
      for (int s = 0; s < 2; ++s)
#pragma unroll
        for (int D = 0; D < 4; ++D) {
          bf16x8s bfv = __builtin_bit_cast(bf16x8s, wfr[h][s][D]);
          acc[h][D] = __builtin_amdgcn_mfma_f32_16x16x32_bf16(af[s], bfv, acc[h][D], 0, 0, 0);
        }
    }
  }

#pragma unroll
  for (int h = 0; h < NH; ++h) {
    float ls = lsum[h];
    ls += __shfl_xor(ls, 16);
    ls += __shfl_xor(ls, 32);
    if (l < 16) Lpart[((size_t)(split * NH + h) << 13) + n0 + w * 16 + l] = ls;
    float* op = Opart + (size_t)(split * NH + h) * N_NODES * HD;
#pragma unroll
    for (int D = 0; D < 4; ++D)
#pragma unroll
      for (int r = 0; r < 4; ++r) {
        int orow = n0 + w * 16 + ((l >> 4) << 2) + r;   // C/D: row=(lane>>4)*4+reg
        op[(size_t)orow * HD + D * 16 + (l & 15)] = acc[h][D][r];
      }
  }
}

// ---------------- kernel 6: combine splits, normalize, ELU, transpose layout
__global__ __launch_bounds__(256) void gat_final_kernel(const float* __restrict__ Opart,
    const float* __restrict__ Lpart, float* __restrict__ out)
{
  int idx = blockIdx.x * 256 + threadIdx.x;
  int n = idx >> 7, c = idx & 127;
  int h = c >> 6, d = c & 63;
  float v = 0.f, ls = 0.f;
#pragma unroll
  for (int sp = 0; sp < MS; ++sp) {
    v  += Opart[((size_t)(sp * NH + h) * N_NODES + n) * HD + d];
    ls += Lpart[(size_t)(sp * NH + h) * N_NODES + n];
  }
  float r = v / fmaxf(ls, 1e-30f);
  out[idx] = (r > 0.f) ? r : (__expf(r) - 1.f);
}

extern "C" void kernel_launch(void* const* d_in, const int* in_sizes, int n_in,
                              void* d_out, int out_size, void* d_ws, size_t ws_size,
                              hipStream_t stream)
{
  const float* hmat = (const float*)d_in[0];
  const int*   adj  = (const int*)d_in[1];
  const float* W    = (const float*)d_in[2];
  const float* a    = (const float*)d_in[3];
  float* out = (float*)d_out;
  char* ws = (char*)d_ws;

  float* u             = (float*)(ws + OFF_U);
  unsigned short* wfrg = (unsigned short*)(ws + OFF_WFRAG);
  float* f1            = (float*)(ws + OFF_F1);
  float* f2            = (float*)(ws + OFF_F2);
  float* f2m           = (float*)(ws + OFF_F2MAX);
  float2* g2           = (float2*)(ws + OFF_G2);
  unsigned short* whb  = (unsigned short*)(ws + OFF_WHB);
  float* Opart         = (float*)(ws + OFF_OP);
  float* Lpart         = (float*)(ws + OFF_LP);

  gat_prep_kernel <<<132, 256, 0, stream>>>(W, a, u, wfrg);
  gat_f12_kernel  <<<N_NODES / 4, 256, 0, stream>>>(hmat, u, f1, f2, g2);
  gat_f2max_kernel<<<NH, 256, 0, stream>>>(f2, f2m);
  gat_wh_kernel   <<<N_NODES / 64, 256, 0, stream>>>(hmat, wfrg, whb);
  gat_attn_kernel <<<128 * MS, 256, 0, stream>>>(adj, whb, f1, g2, f2m, Opart, Lpart);
  gat_final_kernel<<<out_size / 256, 256, 0, stream>>>(Opart, Lpart, out);
}

// Round 8
// 131.048 us; speedup vs baseline: 2.3081x; 2.3081x over previous
//
#include <hip/hip_runtime.h>
#include <hip/hip_bf16.h>
#include <stdint.h>

#define N_NODES 8192
#define IN_F    256
#define HD      64
#define NH      2
#define MS      4                        // column splits
#define SLICE   2048                     // cols per block
#define NT      32                       // 64-col tiles per block
#define ALPHA   0.2f

typedef __attribute__((ext_vector_type(8))) short bf16x8s;
typedef __attribute__((ext_vector_type(4))) float f32x4;

// ws layout (bytes)
#define OFF_U      0          // u[h][v][256] f32                   : 4 KB
#define OFF_WFRAG  4096       // W frag-order [8][8][64][8] bf16    : 64 KB
#define OFF_F1     69632      // f1[2][8192] f32                    : 64 KB
#define OFF_F2     135168     // f2[2][8192] f32                    : 64 KB
#define OFF_F2MAX  200704     // f2max[2] f32 (+pad)
#define OFF_G2     200960     // g2[2][8192] float2                 : 128 KB
#define OFF_WHB    332032     // Wh frag-order [2][128][2][4][64][8] bf16 : 2 MB
#define OFF_OP     2429184    // O partials [MS][2][8192][64] f32   : 16 MB
#define OFF_LP     35983616   // L partials [MS][2][8192] f32       : 256 KB

__device__ __forceinline__ unsigned short f2bf(float x) {
  union { float f; uint32_t u; } c; c.f = x;
  uint32_t r = c.u + 0x7FFFu + ((c.u >> 16) & 1u);   // RNE
  return (unsigned short)(r >> 16);
}
__device__ __forceinline__ short f2bfs(float x) {
  __hip_bfloat16 b = __float2bfloat16(x);
  return __builtin_bit_cast(short, b);
}

// ---------------- kernel 1: u = W·a (f32) + W repacked to B-fragment order (bf16)
__global__ void gat_prep_kernel(const float* __restrict__ W, const float* __restrict__ a,
                                float* __restrict__ u, unsigned short* __restrict__ wfrag)
{
  int idx = blockIdx.x * 256 + threadIdx.x;
  if (idx < 32768) {
    int j = idx & 7, lane = (idx >> 3) & 63, ks = (idx >> 9) & 7, Dt = idx >> 12;
    int k  = ks * 32 + ((lane >> 4) << 3) + j;
    int dp = Dt * 16 + (lane & 15);
    int hh = dp >> 6, d = dp & 63;
    wfrag[idx] = f2bf(W[(size_t)(hh * IN_F + k) * HD + d]);
  } else if (idx < 32768 + NH * 2 * IN_F) {
    int i2 = idx - 32768;
    int i = i2 & 255, v = (i2 >> 8) & 1, h = i2 >> 9;
    const float* Wp = W + (size_t)(h * IN_F + i) * HD;
    const float* ap = a + h * 2 * HD + v * HD;
    float s = 0.f;
    for (int d = 0; d < HD; ++d) s += Wp[d] * ap[d];
    u[(h * 2 + v) * IN_F + i] = s;
  }
}

// ---------------- kernel 2: f1/f2 = h·u, plus per-column exp pairs G1=exp(f2),Ga=exp(a*f2)
__global__ __launch_bounds__(256) void gat_f12_kernel(const float* __restrict__ hmat,
    const float* __restrict__ u, float* __restrict__ f1, float* __restrict__ f2,
    float2* __restrict__ g2)
{
  int n = blockIdx.x * 4 + (threadIdx.x >> 6);
  int l = threadIdx.x & 63;
  float4 hv = *(const float4*)(hmat + (size_t)n * IN_F + l * 4);
  float s[4];
#pragma unroll
  for (int q = 0; q < 4; ++q) {
    float4 uv = *(const float4*)(u + q * IN_F + l * 4);
    s[q] = hv.x * uv.x + hv.y * uv.y + hv.z * uv.z + hv.w * uv.w;
  }
#pragma unroll
  for (int off = 1; off < 64; off <<= 1) {
#pragma unroll
    for (int q = 0; q < 4; ++q) s[q] += __shfl_xor(s[q], off);
  }
  if (l == 0) {
    f1[n] = s[0];           f2[n] = s[1];
    f1[N_NODES + n] = s[2]; f2[N_NODES + n] = s[3];
    g2[n]           = make_float2(__expf(s[1]), __expf(ALPHA * s[1]));
    g2[N_NODES + n] = make_float2(__expf(s[3]), __expf(ALPHA * s[3]));
  }
}

// ---------------- kernel 3: per-head max of f2 (softmax stability bound)
__global__ void gat_f2max_kernel(const float* __restrict__ f2, float* __restrict__ f2m)
{
  int h = blockIdx.x;
  float m = -1e30f;
  for (int i = threadIdx.x; i < N_NODES; i += 256) m = fmaxf(m, f2[h * N_NODES + i]);
#pragma unroll
  for (int off = 1; off < 64; off <<= 1) m = fmaxf(m, __shfl_xor(m, off));
  __shared__ float red[4];
  if ((threadIdx.x & 63) == 0) red[threadIdx.x >> 6] = m;
  __syncthreads();
  if (threadIdx.x == 0) f2m[h] = fmaxf(fmaxf(red[0], red[1]), fmaxf(red[2], red[3]));
}

// ---------------- kernel 4: Wh = h @ W' (bf16 MFMA), epilogue in B-frag order
__global__ __launch_bounds__(256) void gat_wh_kernel(const float* __restrict__ hmat,
    const unsigned short* __restrict__ wfrag, unsigned short* __restrict__ whb)
{
  int tid = threadIdx.x;
  int w = tid >> 6, l = tid & 63;
  int n0 = blockIdx.x * 64;
  int row = n0 + w * 16 + (l & 15);
  f32x4 acc[8] = {};
#pragma unroll
  for (int ks = 0; ks < 8; ++ks) {
    const float* ap = hmat + (size_t)row * IN_F + ks * 32 + ((l >> 4) << 3);
    float av[8];
    *(float4*)&av[0] = *(const float4*)ap;
    *(float4*)&av[4] = *(const float4*)(ap + 4);
    bf16x8s af;
#pragma unroll
    for (int j = 0; j < 8; ++j) af[j] = f2bfs(av[j]);
#pragma unroll
    for (int Dt = 0; Dt < 8; ++Dt) {
      bf16x8s bfv = *(const bf16x8s*)(wfrag + ((size_t)(Dt * 8 + ks) * 64 + l) * 8);
      acc[Dt] = __builtin_amdgcn_mfma_f32_16x16x32_bf16(af, bfv, acc[Dt], 0, 0, 0);
    }
  }
  int Tm = blockIdx.x;
  int s  = w >> 1;
  int lb = ((w & 1) * 2 + ((l >> 4) >> 1)) * 16 + (l & 15);
  int jh = (l >> 4) & 1;
#pragma unroll
  for (int Dt = 0; Dt < 8; ++Dt) {
    int hh = Dt >> 2, D = Dt & 3;
    ushort4 pk;
    pk.x = f2bf(acc[Dt][0]); pk.y = f2bf(acc[Dt][1]);
    pk.z = f2bf(acc[Dt][2]); pk.w = f2bf(acc[Dt][3]);
    size_t off = ((((size_t)(hh * 128 + Tm) * 2 + s) * 4 + D) * 64 + lb) * 8 + jh * 4;
    *(ushort4*)(whb + off) = pk;
  }
}

// ---------------- kernel 5: BARRIER-FREE masked-softmax + PV, spill-safe.
// 16 rows/wave, waves independent (one barrier total, for gl staging).
// whb B-frags direct from global via imm-offset loads on advancing base ptrs;
// adj exact per-fragment int4 reads, 2-deep register prefetch; gl in LDS
// (lgkmcnt pipe — never drains the vmcnt stream).
__global__ __launch_bounds__(256, 2) void gat_attn_kernel(
    const int* __restrict__ adj, const unsigned short* __restrict__ whb,
    const float* __restrict__ f1, const float2* __restrict__ g2,
    const float* __restrict__ f2max, float* __restrict__ Opart, float* __restrict__ Lpart)
{
  int bx = blockIdx.x;                 // grid = 128*MS = 512
  int split = bx & (MS - 1);
  int T = bx >> 2;
  int tid = threadIdx.x;
  int w = tid >> 6, l = tid & 63;
  int n0 = T * 64;
  int row = n0 + w * 16 + (l & 15);
  int mbase = split * SLICE;
  int koff = (l >> 4) << 3;
  int cb = mbase >> 6;                 // whb tile base (32 tiles per split)

  __shared__ float4 gl[2][1024];       // 32 KB: G-pairs per head, whole 2048-col slice

  {
    const float4* s0 = (const float4*)(g2 + mbase);
    const float4* s1 = (const float4*)(g2 + N_NODES + mbase);
#pragma unroll
    for (int i = 0; i < 4; ++i) {
      gl[0][i * 256 + tid] = s0[i * 256 + tid];
      gl[1][i * 256 + tid] = s1[i * 256 + tid];
    }
  }

  float E1[NH], Ea[NH];
#pragma unroll
  for (int h = 0; h < NH; ++h) {
    float f1v = f1[h * N_NODES + row];
    float tm  = f1v + f2max[h];
    float mrow = fmaxf(tm, ALPHA * tm);   // lrelu(f1+f2max) >= all e in this row
    E1[h] = __expf(f1v - mrow);
    Ea[h] = __expf(ALPHA * f1v - mrow);
  }

  __syncthreads();                     // gl visible; only barrier in the kernel

  const int* ap = adj + (size_t)row * N_NODES + mbase + koff;
  // whb frag bases: element index (((h*128 + cb + mt)*2 + s)*4 + D)*64 + l
  const uint4* wp0 = (const uint4*)whb + ((size_t)cb * 8) * 64 + l;         // h=0
  const uint4* wp1 = wp0 + (size_t)128 * 8 * 64;                            // h=1

  // adj 2-deep register prefetch (cur tile + next tile)
  int4 c0 = *(const int4*)(ap);       int4 c1 = *(const int4*)(ap + 4);
  int4 c2 = *(const int4*)(ap + 32);  int4 c3 = *(const int4*)(ap + 36);
  int4 x0 = *(const int4*)(ap + 64);  int4 x1 = *(const int4*)(ap + 68);
  int4 x2 = *(const int4*)(ap + 96);  int4 x3 = *(const int4*)(ap + 100);

  f32x4 acc[NH][4] = {};
  float lsum[NH] = {0.f, 0.f};

#pragma unroll 1
  for (int mt = 0; mt < NT; ++mt) {
    // issue this iter's 16 whb fragment loads (imm offsets off wp0/wp1)
    uint4 wfr[NH][2][4];
#pragma unroll
    for (int s = 0; s < 2; ++s)
#pragma unroll
      for (int D = 0; D < 4; ++D) {
        wfr[0][s][D] = wp0[(s * 4 + D) * 64];
        wfr[1][s][D] = wp1[(s * 4 + D) * 64];
      }
    wp0 += 512; wp1 += 512;            // next tile (8 KB / 16 B)

    int aj[16];
    *(int4*)&aj[0]  = c0; *(int4*)&aj[4]  = c1;
    *(int4*)&aj[8]  = c2; *(int4*)&aj[12] = c3;
    c0 = x0; c1 = x1; c2 = x2; c3 = x3;
    if (mt + 2 < NT) {
      x0 = *(const int4*)(ap + 128); x1 = *(const int4*)(ap + 132);
      x2 = *(const int4*)(ap + 160); x3 = *(const int4*)(ap + 164);
    }
    ap += 64;

#pragma unroll
    for (int h = 0; h < NH; ++h) {
      bf16x8s af[2];
#pragma unroll
      for (int s = 0; s < 2; ++s) {
        const float4* gp = &gl[h][(mt * 64 + s * 32 + koff) >> 1];
        float ps = 0.f;
#pragma unroll
        for (int k = 0; k < 4; ++k) {
          float4 gv = gp[k];
          float v0 = fmaxf(E1[h] * gv.x, Ea[h] * gv.y);
          float v1 = fmaxf(E1[h] * gv.z, Ea[h] * gv.w);
          float p0 = (aj[s * 8 + 2 * k]     > 0) ? v0 : 0.f;
          float p1 = (aj[s * 8 + 2 * k + 1] > 0) ? v1 : 0.f;
          ps += p0 + p1;
          af[s][2 * k] = f2bfs(p0); af[s][2 * k + 1] = f2bfs(p1);
        }
        lsum[h] += ps;
      }
#pragma unroll
      for (int s = 0; s < 2; ++s)
#pragma unroll
        for (int D = 0; D < 4; ++D) {
          bf16x8s bfv = __builtin_bit_cast(bf16x8s, wfr[h][s][D]);
          acc[h][D] = __builtin_amdgcn_mfma_f32_16x16x32_bf16(af[s], bfv, acc[h][D], 0, 0, 0);
        }
    }
  }

#pragma unroll
  for (int h = 0; h < NH; ++h) {
    float ls = lsum[h];
    ls += __shfl_xor(ls, 16);
    ls += __shfl_xor(ls, 32);
    if (l < 16) Lpart[((size_t)(split * NH + h) << 13) + n0 + w * 16 + l] = ls;
    float* op = Opart + (size_t)(split * NH + h) * N_NODES * HD;
#pragma unroll
    for (int D = 0; D < 4; ++D)
#pragma unroll
      for (int r = 0; r < 4; ++r) {
        int orow = n0 + w * 16 + ((l >> 4) << 2) + r;   // C/D: row=(lane>>4)*4+reg
        op[(size_t)orow * HD + D * 16 + (l & 15)] = acc[h][D][r];
      }
  }
}

// ---------------- kernel 6: combine splits, normalize, ELU, transpose layout
__global__ __launch_bounds__(256) void gat_final_kernel(const float* __restrict__ Opart,
    const float* __restrict__ Lpart, float* __restrict__ out)
{
  int idx = blockIdx.x * 256 + threadIdx.x;
  int n = idx >> 7, c = idx & 127;
  int h = c >> 6, d = c & 63;
  float v = 0.f, ls = 0.f;
#pragma unroll
  for (int sp = 0; sp < MS; ++sp) {
    v  += Opart[((size_t)(sp * NH + h) * N_NODES + n) * HD + d];
    ls += Lpart[(size_t)(sp * NH + h) * N_NODES + n];
  }
  float r = v / fmaxf(ls, 1e-30f);
  out[idx] = (r > 0.f) ? r : (__expf(r) - 1.f);
}

extern "C" void kernel_launch(void* const* d_in, const int* in_sizes, int n_in,
                              void* d_out, int out_size, void* d_ws, size_t ws_size,
                              hipStream_t stream)
{
  const float* hmat = (const float*)d_in[0];
  const int*   adj  = (const int*)d_in[1];
  const float* W    = (const float*)d_in[2];
  const float* a    = (const float*)d_in[3];
  float* out = (float*)d_out;
  char* ws = (char*)d_ws;

  float* u             = (float*)(ws + OFF_U);
  unsigned short* wfrg = (unsigned short*)(ws + OFF_WFRAG);
  float* f1            = (float*)(ws + OFF_F1);
  float* f2            = (float*)(ws + OFF_F2);
  float* f2m           = (float*)(ws + OFF_F2MAX);
  float2* g2           = (float2*)(ws + OFF_G2);
  unsigned short* whb  = (unsigned short*)(ws + OFF_WHB);
  float* Opart         = (float*)(ws + OFF_OP);
  float* Lpart         = (float*)(ws + OFF_LP);

  gat_prep_kernel <<<132, 256, 0, stream>>>(W, a, u, wfrg);
  gat_f12_kernel  <<<N_NODES / 4, 256, 0, stream>>>(hmat, u, f1, f2, g2);
  gat_f2max_kernel<<<NH, 256, 0, stream>>>(f2, f2m);
  gat_wh_kernel   <<<N_NODES / 64, 256, 0, stream>>>(hmat, wfrg, whb);
  gat_attn_kernel <<<128 * MS, 256, 0, stream>>>(adj, whb, f1, g2, f2m, Opart, Lpart);
  gat_final_kernel<<<out_size / 256, 256, 0, stream>>>(Opart, Lpart, out);
}

// Round 9
// 113.028 us; speedup vs baseline: 2.6761x; 1.1594x over previous
//
#include <hip/hip_runtime.h>
#include <hip/hip_bf16.h>
#include <stdint.h>

#define N_NODES 8192
#define IN_F    256
#define HD      64
#define NH      2
#define MS      8                        // column splits
#define SLICE   1024                     // cols per block
#define NT      16                       // 64-col tiles per block
#define ALPHA   0.2f

typedef __attribute__((ext_vector_type(8))) short bf16x8s;
typedef __attribute__((ext_vector_type(4))) float f32x4;

// ws layout (bytes)
#define OFF_U      0          // u[h][v][256] f32                   : 4 KB
#define OFF_WFRAG  4096       // W frag-order [8][8][64][8] bf16    : 64 KB
#define OFF_F1     69632      // f1[2][8192] f32                    : 64 KB
#define OFF_F2     135168     // f2[2][8192] f32                    : 64 KB
#define OFF_F2MAX  200704     // f2max[2] f32 (+pad)
#define OFF_G2     200960     // g2b[2][8192] u32 (bf16 g1|ga<<16)  : 64 KB
#define OFF_WHB    332032     // Wh frag-order [2][128][2][4][64][8] bf16 : 2 MB
#define OFF_OP     2429184    // O partials [MS][2][8192][64] f32   : 32 MB
#define OFF_LP     35983616   // L partials [MS][2][8192] f32       : 512 KB

__device__ __forceinline__ unsigned short f2bf(float x) {
  union { float f; uint32_t u; } c; c.f = x;
  uint32_t r = c.u + 0x7FFFu + ((c.u >> 16) & 1u);   // RNE
  return (unsigned short)(r >> 16);
}
__device__ __forceinline__ short f2bfs(float x) {
  __hip_bfloat16 b = __float2bfloat16(x);
  return __builtin_bit_cast(short, b);
}

// ---------------- kernel 1: u = W·a (f32) + W repacked to B-fragment order (bf16)
__global__ void gat_prep_kernel(const float* __restrict__ W, const float* __restrict__ a,
                                float* __restrict__ u, unsigned short* __restrict__ wfrag)
{
  int idx = blockIdx.x * 256 + threadIdx.x;
  if (idx < 32768) {
    int j = idx & 7, lane = (idx >> 3) & 63, ks = (idx >> 9) & 7, Dt = idx >> 12;
    int k  = ks * 32 + ((lane >> 4) << 3) + j;
    int dp = Dt * 16 + (lane & 15);
    int hh = dp >> 6, d = dp & 63;
    wfrag[idx] = f2bf(W[(size_t)(hh * IN_F + k) * HD + d]);
  } else if (idx < 32768 + NH * 2 * IN_F) {
    int i2 = idx - 32768;
    int i = i2 & 255, v = (i2 >> 8) & 1, h = i2 >> 9;
    const float* Wp = W + (size_t)(h * IN_F + i) * HD;
    const float* ap = a + h * 2 * HD + v * HD;
    float s = 0.f;
    for (int d = 0; d < HD; ++d) s += Wp[d] * ap[d];
    u[(h * 2 + v) * IN_F + i] = s;
  }
}

// ---------------- kernel 2: f1/f2 = h·u, plus packed bf16 exp pairs g2b = bf16(e^f2) | bf16(e^{a f2})<<16
__global__ __launch_bounds__(256) void gat_f12_kernel(const float* __restrict__ hmat,
    const float* __restrict__ u, float* __restrict__ f1, float* __restrict__ f2,
    uint32_t* __restrict__ g2b)
{
  int n = blockIdx.x * 4 + (threadIdx.x >> 6);
  int l = threadIdx.x & 63;
  float4 hv = *(const float4*)(hmat + (size_t)n * IN_F + l * 4);
  float s[4];
#pragma unroll
  for (int q = 0; q < 4; ++q) {
    float4 uv = *(const float4*)(u + q * IN_F + l * 4);
    s[q] = hv.x * uv.x + hv.y * uv.y + hv.z * uv.z + hv.w * uv.w;
  }
#pragma unroll
  for (int off = 1; off < 64; off <<= 1) {
#pragma unroll
    for (int q = 0; q < 4; ++q) s[q] += __shfl_xor(s[q], off);
  }
  if (l == 0) {
    f1[n] = s[0];           f2[n] = s[1];
    f1[N_NODES + n] = s[2]; f2[N_NODES + n] = s[3];
    g2b[n]           = (uint32_t)f2bf(__expf(s[1])) | ((uint32_t)f2bf(__expf(ALPHA * s[1])) << 16);
    g2b[N_NODES + n] = (uint32_t)f2bf(__expf(s[3])) | ((uint32_t)f2bf(__expf(ALPHA * s[3])) << 16);
  }
}

// ---------------- kernel 3: per-head max of f2 (softmax stability bound)
__global__ void gat_f2max_kernel(const float* __restrict__ f2, float* __restrict__ f2m)
{
  int h = blockIdx.x;
  float m = -1e30f;
  for (int i = threadIdx.x; i < N_NODES; i += 256) m = fmaxf(m, f2[h * N_NODES + i]);
#pragma unroll
  for (int off = 1; off < 64; off <<= 1) m = fmaxf(m, __shfl_xor(m, off));
  __shared__ float red[4];
  if ((threadIdx.x & 63) == 0) red[threadIdx.x >> 6] = m;
  __syncthreads();
  if (threadIdx.x == 0) f2m[h] = fmaxf(fmaxf(red[0], red[1]), fmaxf(red[2], red[3]));
}

// ---------------- kernel 4: Wh = h @ W' (bf16 MFMA), epilogue in B-frag order
__global__ __launch_bounds__(256) void gat_wh_kernel(const float* __restrict__ hmat,
    const unsigned short* __restrict__ wfrag, unsigned short* __restrict__ whb)
{
  int tid = threadIdx.x;
  int w = tid >> 6, l = tid & 63;
  int n0 = blockIdx.x * 64;
  int row = n0 + w * 16 + (l & 15);
  f32x4 acc[8] = {};
#pragma unroll
  for (int ks = 0; ks < 8; ++ks) {
    const float* ap = hmat + (size_t)row * IN_F + ks * 32 + ((l >> 4) << 3);
    float av[8];
    *(float4*)&av[0] = *(const float4*)ap;
    *(float4*)&av[4] = *(const float4*)(ap + 4);
    bf16x8s af;
#pragma unroll
    for (int j = 0; j < 8; ++j) af[j] = f2bfs(av[j]);
#pragma unroll
    for (int Dt = 0; Dt < 8; ++Dt) {
      bf16x8s bfv = *(const bf16x8s*)(wfrag + ((size_t)(Dt * 8 + ks) * 64 + l) * 8);
      acc[Dt] = __builtin_amdgcn_mfma_f32_16x16x32_bf16(af, bfv, acc[Dt], 0, 0, 0);
    }
  }
  int Tm = blockIdx.x;
  int s  = w >> 1;
  int lb = ((w & 1) * 2 + ((l >> 4) >> 1)) * 16 + (l & 15);
  int jh = (l >> 4) & 1;
#pragma unroll
  for (int Dt = 0; Dt < 8; ++Dt) {
    int hh = Dt >> 2, D = Dt & 3;
    ushort4 pk;
    pk.x = f2bf(acc[Dt][0]); pk.y = f2bf(acc[Dt][1]);
    pk.z = f2bf(acc[Dt][2]); pk.w = f2bf(acc[Dt][3]);
    size_t off = ((((size_t)(hh * 128 + Tm) * 2 + s) * 4 + D) * 64 + lb) * 8 + jh * 4;
    *(ushort4*)(whb + off) = pk;
  }
}

// ---------------- kernel 5: fused masked-softmax + PV. 4-wave blocks, 4 blocks/CU
// (16 waves/CU for adj MLP). whb LDS-staged per block (double-buffered, ONE barrier
// per iter); G-pairs packed bf16 in LDS (8 KB); adj prefetch reloaded mid-iter so
// in-flight loads are old at the barrier drain.
__global__ __launch_bounds__(256, 4) void gat_attn_kernel(
    const int* __restrict__ adj, const unsigned short* __restrict__ whb,
    const float* __restrict__ f1, const uint32_t* __restrict__ g2b,
    const float* __restrict__ f2max, float* __restrict__ Opart, float* __restrict__ Lpart)
{
  int bx = blockIdx.x;                 // grid = 128*MS = 1024
  int split = bx & (MS - 1);
  int T = bx >> 3;
  int tid = threadIdx.x;
  int w = tid >> 6, l = tid & 63;
  int n0 = T * 64;
  int row = n0 + w * 16 + (l & 15);
  int mbase = split * SLICE;
  int koff = (l >> 4) << 3;
  int cb = mbase >> 6;                 // whb tile base

  __shared__ uint32_t glp[2][SLICE];   // 8 KB: packed G pairs per head
  __shared__ uint4 wbuf[2][1024];      // 32 KB: whb tile dbuf (both heads)

  {
    const uint4* s0 = (const uint4*)(g2b + mbase);
    const uint4* s1 = (const uint4*)(g2b + N_NODES + mbase);
    ((uint4*)glp[0])[tid] = s0[tid];
    ((uint4*)glp[1])[tid] = s1[tid];
  }

  float E1[NH], Ea[NH];
#pragma unroll
  for (int h = 0; h < NH; ++h) {
    float f1v = f1[h * N_NODES + row];
    float tm  = f1v + f2max[h];
    float mrow = fmaxf(tm, ALPHA * tm);   // lrelu(f1+f2max) >= all e in this row
    E1[h] = __expf(f1v - mrow);
    Ea[h] = __expf(ALPHA * f1v - mrow);
  }

  const int* ap = adj + (size_t)row * N_NODES + mbase + koff;
  const uint4* wsrc = (const uint4*)whb;   // tile (h,Tm) = 512 uint4 at (h*128+Tm)*512

  // prologue: stage tile 0 + adj tile 0
  uint4 rw0, rw1, rw2, rw3;
  {
    const uint4* w0 = wsrc + (size_t)cb * 512;
    const uint4* w1 = wsrc + (size_t)(128 + cb) * 512;
    rw0 = w0[tid]; rw1 = w0[tid + 256]; rw2 = w1[tid]; rw3 = w1[tid + 256];
  }
  int4 c0 = *(const int4*)(ap);      int4 c1 = *(const int4*)(ap + 4);
  int4 c2 = *(const int4*)(ap + 32); int4 c3 = *(const int4*)(ap + 36);
  wbuf[0][tid]       = rw0; wbuf[0][tid + 256] = rw1;
  wbuf[0][tid + 512] = rw2; wbuf[0][tid + 768] = rw3;
  __syncthreads();

  f32x4 acc[NH][4] = {};
  float lsum[NH] = {0.f, 0.f};

  for (int mt = 0; mt < NT; ++mt) {
    int p = mt & 1;
    // issue next whb tile loads FIRST (L2-hot; waited just before ds_write)
    if (mt + 1 < NT) {
      const uint4* w0 = wsrc + (size_t)(cb + mt + 1) * 512;
      const uint4* w1 = wsrc + (size_t)(128 + cb + mt + 1) * 512;
      rw0 = w0[tid]; rw1 = w0[tid + 256]; rw2 = w1[tid]; rw3 = w1[tid + 256];
    }

    // P-compute: s=0 consumes c0,c1 -> reload; s=1 consumes c2,c3 -> reload.
    bf16x8s af[NH][2];
#pragma unroll
    for (int s = 0; s < 2; ++s) {
      int aj[8];
      if (s == 0) { *(int4*)&aj[0] = c0; *(int4*)&aj[4] = c1; }
      else        { *(int4*)&aj[0] = c2; *(int4*)&aj[4] = c3; }
      uint32_t gv[NH][8];
#pragma unroll
      for (int h = 0; h < NH; ++h) {
        const uint4* gp = (const uint4*)&glp[h][mt * 64 + s * 32 + koff];
        *(uint4*)&gv[h][0] = gp[0];
        *(uint4*)&gv[h][4] = gp[1];
      }
#pragma unroll
      for (int h = 0; h < NH; ++h) {
        float ps = 0.f;
#pragma unroll
        for (int j = 0; j < 8; ++j) {
          uint32_t uv = gv[h][j];
          float g1 = __builtin_bit_cast(float, uv << 16);
          float ga = __builtin_bit_cast(float, uv & 0xffff0000u);
          float v  = fmaxf(E1[h] * g1, Ea[h] * ga);
          float pz = (aj[j] > 0) ? v : 0.f;
          ps += pz;
          af[h][s][j] = f2bfs(pz);
        }
        lsum[h] += ps;
      }
      // mid-iter adj reload for tile mt+1 (ages ~full MFMA+write phase before barrier)
      if (mt + 1 < NT) {
        const int* apn = ap + (mt + 1) * 64;
        if (s == 0) { c0 = *(const int4*)(apn);      c1 = *(const int4*)(apn + 4); }
        else        { c2 = *(const int4*)(apn + 32); c3 = *(const int4*)(apn + 36); }
      }
    }

    // MFMA from current LDS buffer
    const unsigned short* lb = (const unsigned short*)wbuf[p];
#pragma unroll
    for (int h = 0; h < NH; ++h)
#pragma unroll
      for (int s = 0; s < 2; ++s)
#pragma unroll
        for (int D = 0; D < 4; ++D) {
          bf16x8s bfv = *(const bf16x8s*)&lb[(h * 8 + s * 4 + D) * 512 + l * 8];
          acc[h][D] = __builtin_amdgcn_mfma_f32_16x16x32_bf16(af[h][s], bfv, acc[h][D], 0, 0, 0);
        }

    // write next tile into other buffer; single barrier per iteration
    if (mt + 1 < NT) {
      wbuf[p ^ 1][tid]       = rw0; wbuf[p ^ 1][tid + 256] = rw1;
      wbuf[p ^ 1][tid + 512] = rw2; wbuf[p ^ 1][tid + 768] = rw3;
    }
    __syncthreads();
  }

#pragma unroll
  for (int h = 0; h < NH; ++h) {
    float ls = lsum[h];
    ls += __shfl_xor(ls, 16);
    ls += __shfl_xor(ls, 32);
    if (l < 16) Lpart[((size_t)(split * NH + h) << 13) + n0 + w * 16 + l] = ls;
    float* op = Opart + (size_t)(split * NH + h) * N_NODES * HD;
#pragma unroll
    for (int D = 0; D < 4; ++D)
#pragma unroll
      for (int r = 0; r < 4; ++r) {
        int orow = n0 + w * 16 + ((l >> 4) << 2) + r;   // C/D: row=(lane>>4)*4+reg
        op[(size_t)orow * HD + D * 16 + (l & 15)] = acc[h][D][r];
      }
  }
}

// ---------------- kernel 6: combine splits, normalize, ELU, transpose layout
__global__ __launch_bounds__(256) void gat_final_kernel(const float* __restrict__ Opart,
    const float* __restrict__ Lpart, float* __restrict__ out)
{
  int idx = blockIdx.x * 256 + threadIdx.x;
  int n = idx >> 7, c = idx & 127;
  int h = c >> 6, d = c & 63;
  float v = 0.f, ls = 0.f;
#pragma unroll
  for (int sp = 0; sp < MS; ++sp) {
    v  += Opart[((size_t)(sp * NH + h) * N_NODES + n) * HD + d];
    ls += Lpart[(size_t)(sp * NH + h) * N_NODES + n];
  }
  float r = v / fmaxf(ls, 1e-30f);
  out[idx] = (r > 0.f) ? r : (__expf(r) - 1.f);
}

extern "C" void kernel_launch(void* const* d_in, const int* in_sizes, int n_in,
                              void* d_out, int out_size, void* d_ws, size_t ws_size,
                              hipStream_t stream)
{
  const float* hmat = (const float*)d_in[0];
  const int*   adj  = (const int*)d_in[1];
  const float* W    = (const float*)d_in[2];
  const float* a    = (const float*)d_in[3];
  float* out = (float*)d_out;
  char* ws = (char*)d_ws;

  float* u             = (float*)(ws + OFF_U);
  unsigned short* wfrg = (unsigned short*)(ws + OFF_WFRAG);
  float* f1            = (float*)(ws + OFF_F1);
  float* f2            = (float*)(ws + OFF_F2);
  float* f2m           = (float*)(ws + OFF_F2MAX);
  uint32_t* g2b        = (uint32_t*)(ws + OFF_G2);
  unsigned short* whb  = (unsigned short*)(ws + OFF_WHB);
  float* Opart         = (float*)(ws + OFF_OP);
  float* Lpart         = (float*)(ws + OFF_LP);

  gat_prep_kernel <<<132, 256, 0, stream>>>(W, a, u, wfrg);
  gat_f12_kernel  <<<N_NODES / 4, 256, 0, stream>>>(hmat, u, f1, f2, g2b);
  gat_f2max_kernel<<<NH, 256, 0, stream>>>(f2, f2m);
  gat_wh_kernel   <<<N_NODES / 64, 256, 0, stream>>>(hmat, wfrg, whb);
  gat_attn_kernel <<<128 * MS, 256, 0, stream>>>(adj, whb, f1, g2b, f2m, Opart, Lpart);
  gat_final_kernel<<<out_size / 256, 256, 0, stream>>>(Opart, Lpart, out);
}